// Round 15
// baseline (169.678 us; speedup 1.0000x reference)
//
#include <hip/hip_runtime.h>
#include <hip/hip_bf16.h>

// LowRankAttention: kv = x @ Wkv^T ; S = routers @ kv^T * scale ; P = softmax(S)
// ; AO = P @ kv ; out = AO @ Wproj^T + bias.  All GEMMs bf16 MFMA (f32 accum).
// Shapes: bs=32 ns=512 seq=1024 H=8 d_r=64 d_model=256.

typedef __attribute__((ext_vector_type(8))) short short8;
typedef __attribute__((ext_vector_type(4))) float f32x4;
typedef __attribute__((ext_vector_type(4))) unsigned int uint4v;
typedef __attribute__((ext_vector_type(4))) unsigned short ushort4v;

__device__ inline unsigned short f2bf(float f) {
  unsigned int u = __float_as_uint(f);
  u += 0x7FFFu + ((u >> 16) & 1u);   // RNE
  return (unsigned short)(u >> 16);
}

__device__ __forceinline__ void async_copy16(unsigned short* lds, const unsigned short* g) {
  __builtin_amdgcn_global_load_lds(
      (const __attribute__((address_space(1))) unsigned int*)g,
      (__attribute__((address_space(3))) unsigned int*)lds,
      16, 0, 0);
}

// casts wkv (524288 f4) | projw (524288 f4) | x (4194304 f4) AND zeroes out0
// (524288 f4) — all boundaries are multiples of 256 so branches are block-uniform.
__global__ __launch_bounds__(256) void cast_all(
    const float* __restrict__ x, const float* __restrict__ wkv, const float* __restrict__ projw,
    unsigned short* __restrict__ xb, unsigned short* __restrict__ wkv_b,
    unsigned short* __restrict__ projw_b, float* __restrict__ out0) {
  int i = blockIdx.x * 256 + threadIdx.x;
  if (i >= 5242880) {                                   // zero out0 (proj accumulates)
    ((float4*)out0)[i - 5242880] = float4{0.f, 0.f, 0.f, 0.f};
    return;
  }
  const float* src; unsigned short* dst; int off;
  if (i < 524288)        { src = wkv;   dst = wkv_b;   off = i; }
  else if (i < 1048576)  { src = projw; dst = projw_b; off = i - 524288; }
  else                   { src = x;     dst = xb;      off = i - 1048576; }
  float4 v = ((const float4*)src)[off];
  ushort4v w; w.x = f2bf(v.x); w.y = f2bf(v.y); w.z = f2bf(v.z); w.w = f2bf(v.w);
  ((ushort4v*)dst)[off] = w;
}

// ============ 256x256 8-phase GEMM (round-7/11 proven version, ~900 TF) ============
// 512 thr = 8 waves (2M x 4N); BK=64 as two k-halves of 32. LDS 128 KiB, gload_lds
// width-16, ONE barrier per phase, counted vmcnt(6) at tile end, both-sides swizzle
// (bank-conflict 0 measured). 16x16x32 MFMA — 32x32 variants measured WORSE (R12/R13).
// Do not re-pin the schedule (round-8 regression).
__global__ __launch_bounds__(512, 1) void gemm1_8phase(
    const unsigned short* __restrict__ A, const unsigned short* __restrict__ B,
    unsigned short* __restrict__ C, int lda, int ldb, int ldc, int K, int nWGn)
{
  __shared__ __align__(16) unsigned short sA[2][2][8192];
  __shared__ __align__(16) unsigned short sB[2][2][8192];

  const int tid = threadIdx.x;
  const int cpx = gridDim.x >> 3;
  const int swz = (blockIdx.x & 7) * cpx + (blockIdx.x >> 3);
  const int bn = swz % nWGn, bm = swz / nWGn;

  const int wave = tid >> 6, lane = tid & 63;
  const int wm = wave >> 2, wn = wave & 3;
  const int lr = lane & 15, ls = lane >> 4;
  const int lsw8 = (ls ^ ((lr >> 1) & 3)) * 8;

  const int r0 = tid >> 2;
  const int sl0 = (tid & 3) ^ ((tid >> 3) & 3);
  const unsigned short* gA = A + (long long)(bm * 256 + r0) * lda + sl0 * 8;
  const unsigned short* gB = B + (long long)(bn * 256 + r0) * ldb + sl0 * 8;
  const long long lda128 = (long long)128 * lda, ldb128 = (long long)128 * ldb;

#define STA(b_, k_, t_) { const unsigned short* g_ = gA + (t_) * 64 + (k_) * 32; \
    async_copy16(&sA[b_][k_][tid * 8], g_); \
    async_copy16(&sA[b_][k_][4096 + tid * 8], g_ + lda128); }
#define STB(b_, k_, t_) { const unsigned short* g_ = gB + (t_) * 64 + (k_) * 32; \
    async_copy16(&sB[b_][k_][tid * 8], g_); \
    async_copy16(&sB[b_][k_][4096 + tid * 8], g_ + ldb128); }

  f32x4 acc[8][4];
  #pragma unroll
  for (int mi = 0; mi < 8; ++mi)
    #pragma unroll
    for (int ni = 0; ni < 4; ++ni)
      acc[mi][ni] = f32x4{0.f, 0.f, 0.f, 0.f};

  const int KT = K >> 6;
  STB(0, 0, 0) STA(0, 0, 0) STB(0, 1, 0) STA(0, 1, 0)
  if (KT > 1) {
    STB(1, 0, 1) STA(1, 0, 1) STB(1, 1, 1)
    asm volatile("s_waitcnt vmcnt(6)" ::: "memory");
  } else {
    asm volatile("s_waitcnt vmcnt(0)" ::: "memory");
  }
  __builtin_amdgcn_s_barrier();
  __builtin_amdgcn_sched_barrier(0);

  for (int t = 0; t < KT; ++t) {
    const int b = t & 1, nb = b ^ 1;
    const bool hasT1 = (t + 1) < KT, hasT2 = (t + 2) < KT;
    short8 af[4], bf[4];

    // ---- P1: (mh=0, kk=0) ----
    #pragma unroll
    for (int mi = 0; mi < 4; ++mi)
      af[mi] = *(const short8*)&sA[b][0][(wm * 128 + mi * 16 + lr) * 32 + lsw8];
    #pragma unroll
    for (int ni = 0; ni < 4; ++ni)
      bf[ni] = *(const short8*)&sB[b][0][(wn * 64 + ni * 16 + lr) * 32 + lsw8];
    if (hasT1) { STA(nb, 1, t + 1) }
    __builtin_amdgcn_s_setprio(1);
    #pragma unroll
    for (int mi = 0; mi < 4; ++mi)
      #pragma unroll
      for (int ni = 0; ni < 4; ++ni)
        acc[mi][ni] = __builtin_amdgcn_mfma_f32_16x16x32_bf16(af[mi], bf[ni], acc[mi][ni], 0, 0, 0);
    __builtin_amdgcn_s_setprio(0);
    __builtin_amdgcn_s_barrier();

    // ---- P2: (mh=1, kk=0) ----
    #pragma unroll
    for (int mi = 0; mi < 4; ++mi)
      af[mi] = *(const short8*)&sA[b][0][(wm * 128 + (4 + mi) * 16 + lr) * 32 + lsw8];
    if (hasT2) { STB(b, 0, t + 2) }
    __builtin_amdgcn_s_setprio(1);
    #pragma unroll
    for (int mi = 0; mi < 4; ++mi)
      #pragma unroll
      for (int ni = 0; ni < 4; ++ni)
        acc[4 + mi][ni] = __builtin_amdgcn_mfma_f32_16x16x32_bf16(af[mi], bf[ni], acc[4 + mi][ni], 0, 0, 0);
    __builtin_amdgcn_s_setprio(0);
    __builtin_amdgcn_s_barrier();

    // ---- P3: (mh=0, kk=1) ----
    #pragma unroll
    for (int mi = 0; mi < 4; ++mi)
      af[mi] = *(const short8*)&sA[b][1][(wm * 128 + mi * 16 + lr) * 32 + lsw8];
    #pragma unroll
    for (int ni = 0; ni < 4; ++ni)
      bf[ni] = *(const short8*)&sB[b][1][(wn * 64 + ni * 16 + lr) * 32 + lsw8];
    if (hasT2) { STA(b, 0, t + 2) }
    __builtin_amdgcn_s_setprio(1);
    #pragma unroll
    for (int mi = 0; mi < 4; ++mi)
      #pragma unroll
      for (int ni = 0; ni < 4; ++ni)
        acc[mi][ni] = __builtin_amdgcn_mfma_f32_16x16x32_bf16(af[mi], bf[ni], acc[mi][ni], 0, 0, 0);
    __builtin_amdgcn_s_setprio(0);
    __builtin_amdgcn_s_barrier();

    // ---- P4: (mh=1, kk=1) ----
    #pragma unroll
    for (int mi = 0; mi < 4; ++mi)
      af[mi] = *(const short8*)&sA[b][1][(wm * 128 + (4 + mi) * 16 + lr) * 32 + lsw8];
    if (hasT2) { STB(b, 1, t + 2) }
    __builtin_amdgcn_s_setprio(1);
    #pragma unroll
    for (int mi = 0; mi < 4; ++mi)
      #pragma unroll
      for (int ni = 0; ni < 4; ++ni)
        acc[4 + mi][ni] = __builtin_amdgcn_mfma_f32_16x16x32_bf16(af[mi], bf[ni], acc[4 + mi][ni], 0, 0, 0);
    __builtin_amdgcn_s_setprio(0);
    if (t == KT - 2) {
      asm volatile("s_waitcnt vmcnt(0)" ::: "memory");
    } else if (t < KT - 2) {
      asm volatile("s_waitcnt vmcnt(6)" ::: "memory");
    }
    __builtin_amdgcn_s_barrier();
    __builtin_amdgcn_sched_barrier(0);
  }
#undef STA
#undef STB

  #pragma unroll
  for (int mi = 0; mi < 8; ++mi) {
    #pragma unroll
    for (int ni = 0; ni < 4; ++ni) {
      int row = bm * 256 + wm * 128 + mi * 16 + ls * 4;
      int col = bn * 256 + wn * 64 + ni * 16 + lr;
      #pragma unroll
      for (int r = 0; r < 4; ++r)
        C[(long long)(row + r) * ldc + col] = f2bf(acc[mi][ni][r]);
    }
  }
}

// ======== fused score+softmax+PV: one wg per (b,h), 1024 thr / 16 waves ========
// (round-14 proven, incl. hoisted dt=0 kvT staging overlapping softmax).
// LDS carve (148 KiB): lds_a 9216 | lds_b 73728 (P aliases) | kvT 66560 | red 2048.
__global__ __launch_bounds__(1024, 1) void score_softmax_pv(
    const float* __restrict__ routers,      // f32 (8,64,256)
    const unsigned short* __restrict__ kv,  // (16384,2048): row b*512+n, col h*256+d
    float* __restrict__ attnw,              // (256,64,512) f32
    unsigned short* __restrict__ ao)        // (2048,2048): row b*64+r, col h*256+d
{
  __shared__ __align__(16) char smem[151552];
  unsigned short* lds_a = (unsigned short*)smem;                 // [64][72]
  unsigned short* lds_b = (unsigned short*)(smem + 9216);        // [512][72] kv tiles
  unsigned short* P_lds = (unsigned short*)(smem + 9216);        // [64][520] (aliases lds_b)
  unsigned short* kvT   = (unsigned short*)(smem + 82944);       // [64][520]
  float* redmax = (float*)(smem + 149504);                       // [64][4]
  float* redsum = (float*)(smem + 150528);                       // [64][4]

  const int bh = blockIdx.x;
  const int b = bh >> 3, h = bh & 7;
  const int tid = threadIdx.x;
  const int wave = tid >> 6, lane = tid & 63;
  const int wm = wave >> 2, wn = wave & 3;
  const int lr = lane & 15, ls = lane >> 4;
  const int lk = ls * 8;

  const unsigned short* kvb = kv + (long long)b * 512 * 2048 + h * 256;
  const float* Rh = routers + h * 16384;

#define STAGE_KVT(dt_) { _Pragma("unroll") \
    for (int i = 0; i < 4; ++i) { \
      int c = i * 1024 + tid; \
      int n = c & 511, dgrp = c >> 9; \
      uint4v v = *(const uint4v*)&kvb[(long long)n * 2048 + (dt_) * 64 + dgrp * 8]; \
      const unsigned short* pv = (const unsigned short*)&v; \
      _Pragma("unroll") \
      for (int j = 0; j < 8; ++j) kvT[(dgrp * 8 + j) * 520 + n] = pv[j]; \
    } }

  f32x4 acc[8];
  #pragma unroll
  for (int ni = 0; ni < 8; ++ni) acc[ni] = f32x4{0.f, 0.f, 0.f, 0.f};

  // ---- score ----
  for (int k0 = 0; k0 < 256; k0 += 64) {
    {
      int r = tid >> 4, kc = (tid & 15) * 4;
      float4 v = *(const float4*)(Rh + r * 256 + k0 + kc);
      ushort4v w; w.x = f2bf(v.x); w.y = f2bf(v.y); w.z = f2bf(v.z); w.w = f2bf(v.w);
      *(ushort4v*)&lds_a[r * 72 + kc] = w;
    }
    #pragma unroll
    for (int i = 0; i < 4; ++i) {
      int c = i * 1024 + tid;
      int r = c >> 3, kc = (c & 7) * 8;
      *(uint4v*)&lds_b[r * 72 + kc] = *(const uint4v*)(kvb + (long long)r * 2048 + k0 + kc);
    }
    __syncthreads();
    #pragma unroll
    for (int kk = 0; kk < 2; ++kk) {
      short8 af = *(const short8*)&lds_a[(wm * 16 + lr) * 72 + kk * 32 + lk];
      #pragma unroll
      for (int ni = 0; ni < 8; ++ni) {
        short8 bf = *(const short8*)&lds_b[(wn * 128 + ni * 16 + lr) * 72 + kk * 32 + lk];
        acc[ni] = __builtin_amdgcn_mfma_f32_16x16x32_bf16(af, bf, acc[ni], 0, 0, 0);
      }
    }
    __syncthreads();
  }

  // hoisted dt=0 kvT staging — overlaps softmax below (kvT disjoint; published
  // by the first PV __syncthreads)
  STAGE_KVT(0)

  // ---- softmax ----
  #pragma unroll
  for (int q = 0; q < 4; ++q) {
    int row = wm * 16 + ls * 4 + q;
    float m = -1e30f;
    #pragma unroll
    for (int ni = 0; ni < 8; ++ni) { acc[ni][q] *= 0.0625f; m = fmaxf(m, acc[ni][q]); }
    #pragma unroll
    for (int d = 1; d < 16; d <<= 1) m = fmaxf(m, __shfl_xor(m, d, 64));
    if (lr == 0) redmax[row * 4 + wn] = m;
  }
  __syncthreads();
  #pragma unroll
  for (int q = 0; q < 4; ++q) {
    int row = wm * 16 + ls * 4 + q;
    float M = fmaxf(fmaxf(redmax[row * 4 + 0], redmax[row * 4 + 1]),
                    fmaxf(redmax[row * 4 + 2], redmax[row * 4 + 3]));
    float s = 0.f;
    #pragma unroll
    for (int ni = 0; ni < 8; ++ni) { float p = __expf(acc[ni][q] - M); acc[ni][q] = p; s += p; }
    #pragma unroll
    for (int d = 1; d < 16; d <<= 1) s += __shfl_xor(s, d, 64);
    if (lr == 0) redsum[row * 4 + wn] = s;
  }
  __syncthreads();
  #pragma unroll
  for (int q = 0; q < 4; ++q) {
    int row = wm * 16 + ls * 4 + q;
    float inv = 1.0f / (redsum[row * 4 + 0] + redsum[row * 4 + 1] +
                        redsum[row * 4 + 2] + redsum[row * 4 + 3]);
    long long base = (long long)bh * 32768 + row * 512 + wn * 128;
    #pragma unroll
    for (int ni = 0; ni < 8; ++ni) {
      float wv = acc[ni][q] * inv;
      attnw[base + ni * 16 + lr] = wv;
      P_lds[row * 520 + wn * 128 + ni * 16 + lr] = f2bf(wv);   // aliases dead lds_b
    }
  }

  // ---- PV: 4 d-tiles of 64 (dt=0 staging already done) ----
  for (int dt = 0; dt < 4; ++dt) {
    if (dt != 0) { STAGE_KVT(dt) }
    __syncthreads();   // covers P_lds writes + kvT staging
    f32x4 accp = f32x4{0.f, 0.f, 0.f, 0.f};
    #pragma unroll
    for (int kk = 0; kk < 16; ++kk) {
      short8 af = *(const short8*)&P_lds[(wm * 16 + lr) * 520 + kk * 32 + lk];
      short8 bf = *(const short8*)&kvT[(wn * 16 + lr) * 520 + kk * 32 + lk];
      accp = __builtin_amdgcn_mfma_f32_16x16x32_bf16(af, bf, accp, 0, 0, 0);
    }
    #pragma unroll
    for (int q = 0; q < 4; ++q) {
      int r = wm * 16 + ls * 4 + q;
      ao[(long long)(b * 64 + r) * 2048 + h * 256 + dt * 64 + wn * 16 + lr] = f2bf(accp[q]);
    }
    __syncthreads();   // before next tile's kvT overwrite
  }
#undef STAGE_KVT
}

// ---------------- proj: m97-structure gemm (gload_lds) + split-K atomic ----------------
// C[m,n] += sum_k A[m,k]*B[n,k] over K-slice kp (blockIdx.y). 128x128 tile, BK=64,
// 4 waves (2x2, wave 64x64), gload_lds width-16 into LINEAR LDS, 2 barriers/K-step
// (round-3-proven skeleton). out0 pre-zeroed by cast_all; 4 commutative f32 atomic
// adds per element (bias folded into kp==0) — rounding variance << 4.8e-3 threshold.
__global__ __launch_bounds__(256) void proj_glds_splitk(
    const unsigned short* __restrict__ A, const unsigned short* __restrict__ B,
    float* __restrict__ C, const float* __restrict__ bias,
    int lda, int ldb, int ldc, int Kslice, int nWGn)
{
  __shared__ __align__(16) unsigned short sA[128 * 64];
  __shared__ __align__(16) unsigned short sB[128 * 64];

  const int tid = threadIdx.x;
  const int bn = blockIdx.x % nWGn;
  const int bm = blockIdx.x / nWGn;
  const int kp = blockIdx.y;

  const int wave = tid >> 6, lane = tid & 63;
  const int wm = wave >> 1, wn = wave & 1;
  const int lr = lane & 15;
  const int lk = (lane >> 4) * 8;

  // staging: issue i (0..3) covers rows i*32 + tid/8, cols (tid%8)*8 (bf16)
  const unsigned short* Ab = A + (long long)(bm * 128 + (tid >> 3)) * lda + (tid & 7) * 8
                               + (long long)kp * Kslice;
  const unsigned short* Bb = B + (long long)(bn * 128 + (tid >> 3)) * ldb + (tid & 7) * 8
                               + (long long)kp * Kslice;
  unsigned short* sAp = &sA[tid * 8];
  unsigned short* sBp = &sB[tid * 8];

  f32x4 acc[4][4];
  #pragma unroll
  for (int mi = 0; mi < 4; ++mi)
    #pragma unroll
    for (int ni = 0; ni < 4; ++ni)
      acc[mi][ni] = f32x4{0.f, 0.f, 0.f, 0.f};

  for (int k0 = 0; k0 < Kslice; k0 += 64) {
    #pragma unroll
    for (int i = 0; i < 4; ++i) {
      async_copy16(sAp + i * 2048, Ab + (long long)i * 32 * lda + k0);
      async_copy16(sBp + i * 2048, Bb + (long long)i * 32 * ldb + k0);
    }
    __syncthreads();

    #pragma unroll
    for (int kk = 0; kk < 2; ++kk) {
      short8 af[4], bfr[4];
      #pragma unroll
      for (int mi = 0; mi < 4; ++mi)
        af[mi] = *(const short8*)&sA[(wm * 64 + mi * 16 + lr) * 64 + kk * 32 + lk];
      #pragma unroll
      for (int ni = 0; ni < 4; ++ni)
        bfr[ni] = *(const short8*)&sB[(wn * 64 + ni * 16 + lr) * 64 + kk * 32 + lk];
      #pragma unroll
      for (int mi = 0; mi < 4; ++mi)
        #pragma unroll
        for (int ni = 0; ni < 4; ++ni)
          acc[mi][ni] = __builtin_amdgcn_mfma_f32_16x16x32_bf16(af[mi], bfr[ni], acc[mi][ni], 0, 0, 0);
    }
    __syncthreads();
  }

  const int cr0 = (lane >> 4) * 4;
  #pragma unroll
  for (int mi = 0; mi < 4; ++mi) {
    #pragma unroll
    for (int ni = 0; ni < 4; ++ni) {
      int row = bm * 128 + wm * 64 + mi * 16 + cr0;
      int col = bn * 128 + wn * 64 + ni * 16 + lr;
      float badd = (kp == 0) ? bias[col] : 0.f;
      #pragma unroll
      for (int r = 0; r < 4; ++r)
        unsafeAtomicAdd(&C[(long long)(row + r) * ldc + col], acc[mi][ni][r] + badd);
    }
  }
}

extern "C" void kernel_launch(void* const* d_in, const int* in_sizes, int n_in,
                              void* d_out, int out_size, void* d_ws, size_t ws_size,
                              hipStream_t stream) {
  const float* x       = (const float*)d_in[0];   // (32,512,1024)
  const float* routers = (const float*)d_in[1];   // (8,64,256)
  const float* wkv     = (const float*)d_in[2];   // (2048,1024)
  const float* projw   = (const float*)d_in[3];   // (1024,2048)
  const float* pbias   = (const float*)d_in[4];   // (1024,)

  char* ws = (char*)d_ws;
  unsigned short* wkv_b   = (unsigned short*)(ws);                //  4,194,304 B
  unsigned short* projw_b = (unsigned short*)(ws +  4194304);     //  4,194,304 B
  unsigned short* kv_b    = (unsigned short*)(ws +  8388608);     // 67,108,864 B (16384 x 2048)
  // region R: xb lives here ONLY during gemm1; ao_b reuses it afterwards.
  unsigned short* xb      = (unsigned short*)(ws + 75497472);     // 33,554,432 B (16384 x 1024)
  unsigned short* ao_b    = (unsigned short*)(ws + 92536832);     //  8,388,608 B (2048 x 2048)

  float* out0  = (float*)d_out;            // (32,64,1024)
  float* attnw = out0 + 2097152;           // (32,8,64,512) f32 softmax output

  // cast wkv | projw | x  +  zero out0 (5,767,168 float4 units)
  cast_all<<<22528, 256, 0, stream>>>(x, wkv, projw, xb, wkv_b, projw_b, out0);

  // kv = x @ wkv^T : M=16384 N=2048 K=1024 -> bf16 kv_b ; grid 64x8 = 512 wgs
  gemm1_8phase<<<512, 512, 0, stream>>>(xb, wkv_b, kv_b, 1024, 1024, 2048, 1024, 8);

  // fused S = routers@kv^T/16 + softmax -> attnw, then AO = P@kv -> ao_b; 1 wg per bh
  score_softmax_pv<<<256, 1024, 0, stream>>>(routers, kv_b, attnw, ao_b);

  // out += AO @ projw^T (+bias on kp==0) : M=2048 N=1024, K split 4x512, m97-structure
  proj_glds_splitk<<<dim3(128, 4), 256, 0, stream>>>(
      ao_b, projw_b, out0, pbias, 2048, 2048, 1024, 512, 8);
}

// Round 16
// 160.366 us; speedup vs baseline: 1.0581x; 1.0581x over previous
//
#include <hip/hip_runtime.h>
#include <hip/hip_bf16.h>

// LowRankAttention: kv = x @ Wkv^T ; S = routers @ kv^T * scale ; P = softmax(S)
// ; AO = P @ kv ; out = AO @ Wproj^T + bias.  All GEMMs bf16 MFMA (f32 accum).
// Shapes: bs=32 ns=512 seq=1024 H=8 d_r=64 d_model=256.
// FINAL (R14 config, session best 160.5 µs): cast_all + gemm1_8phase (16x16x32,
// one-barrier/phase, vmcnt(6), both-sides swizzle, XCD swizzle) + fused
// score_softmax_pv (hoisted kvT dt=0) + 2-way split-K proj.

typedef __attribute__((ext_vector_type(8))) short short8;
typedef __attribute__((ext_vector_type(4))) float f32x4;
typedef __attribute__((ext_vector_type(4))) unsigned int uint4v;
typedef __attribute__((ext_vector_type(4))) unsigned short ushort4v;

__device__ inline unsigned short f2bf(float f) {
  unsigned int u = __float_as_uint(f);
  u += 0x7FFFu + ((u >> 16) & 1u);   // RNE
  return (unsigned short)(u >> 16);
}

__device__ __forceinline__ void async_copy16(unsigned short* lds, const unsigned short* g) {
  __builtin_amdgcn_global_load_lds(
      (const __attribute__((address_space(1))) unsigned int*)g,
      (__attribute__((address_space(3))) unsigned int*)lds,
      16, 0, 0);
}

// casts wkv (524288 f4) | projw (524288 f4) | x (4194304 f4) AND zeroes out0
// (524288 f4) — all boundaries are multiples of 256 so branches are block-uniform.
__global__ __launch_bounds__(256) void cast_all(
    const float* __restrict__ x, const float* __restrict__ wkv, const float* __restrict__ projw,
    unsigned short* __restrict__ xb, unsigned short* __restrict__ wkv_b,
    unsigned short* __restrict__ projw_b, float* __restrict__ out0) {
  int i = blockIdx.x * 256 + threadIdx.x;
  if (i >= 5242880) {                                   // zero out0 (proj accumulates)
    ((float4*)out0)[i - 5242880] = float4{0.f, 0.f, 0.f, 0.f};
    return;
  }
  const float* src; unsigned short* dst; int off;
  if (i < 524288)        { src = wkv;   dst = wkv_b;   off = i; }
  else if (i < 1048576)  { src = projw; dst = projw_b; off = i - 524288; }
  else                   { src = x;     dst = xb;      off = i - 1048576; }
  float4 v = ((const float4*)src)[off];
  ushort4v w; w.x = f2bf(v.x); w.y = f2bf(v.y); w.z = f2bf(v.z); w.w = f2bf(v.w);
  ((ushort4v*)dst)[off] = w;
}

// ============ 256x256 8-phase GEMM (round-7/11 proven version, ~900 TF) ============
// 512 thr = 8 waves (2M x 4N); BK=64 as two k-halves of 32. LDS 128 KiB, gload_lds
// width-16, ONE barrier per phase, counted vmcnt(6) at tile end, both-sides swizzle
// (bank-conflict 0 measured). 16x16x32 MFMA — 32x32 variants measured WORSE (R12/R13:
// +6.3M bank conflicts from the changed read geometry). Do not re-pin the schedule
// (round-8 regression).
__global__ __launch_bounds__(512, 1) void gemm1_8phase(
    const unsigned short* __restrict__ A, const unsigned short* __restrict__ B,
    unsigned short* __restrict__ C, int lda, int ldb, int ldc, int K, int nWGn)
{
  __shared__ __align__(16) unsigned short sA[2][2][8192];
  __shared__ __align__(16) unsigned short sB[2][2][8192];

  const int tid = threadIdx.x;
  const int cpx = gridDim.x >> 3;
  const int swz = (blockIdx.x & 7) * cpx + (blockIdx.x >> 3);
  const int bn = swz % nWGn, bm = swz / nWGn;

  const int wave = tid >> 6, lane = tid & 63;
  const int wm = wave >> 2, wn = wave & 3;
  const int lr = lane & 15, ls = lane >> 4;
  const int lsw8 = (ls ^ ((lr >> 1) & 3)) * 8;

  const int r0 = tid >> 2;
  const int sl0 = (tid & 3) ^ ((tid >> 3) & 3);
  const unsigned short* gA = A + (long long)(bm * 256 + r0) * lda + sl0 * 8;
  const unsigned short* gB = B + (long long)(bn * 256 + r0) * ldb + sl0 * 8;
  const long long lda128 = (long long)128 * lda, ldb128 = (long long)128 * ldb;

#define STA(b_, k_, t_) { const unsigned short* g_ = gA + (t_) * 64 + (k_) * 32; \
    async_copy16(&sA[b_][k_][tid * 8], g_); \
    async_copy16(&sA[b_][k_][4096 + tid * 8], g_ + lda128); }
#define STB(b_, k_, t_) { const unsigned short* g_ = gB + (t_) * 64 + (k_) * 32; \
    async_copy16(&sB[b_][k_][tid * 8], g_); \
    async_copy16(&sB[b_][k_][4096 + tid * 8], g_ + ldb128); }

  f32x4 acc[8][4];
  #pragma unroll
  for (int mi = 0; mi < 8; ++mi)
    #pragma unroll
    for (int ni = 0; ni < 4; ++ni)
      acc[mi][ni] = f32x4{0.f, 0.f, 0.f, 0.f};

  const int KT = K >> 6;
  STB(0, 0, 0) STA(0, 0, 0) STB(0, 1, 0) STA(0, 1, 0)
  if (KT > 1) {
    STB(1, 0, 1) STA(1, 0, 1) STB(1, 1, 1)
    asm volatile("s_waitcnt vmcnt(6)" ::: "memory");
  } else {
    asm volatile("s_waitcnt vmcnt(0)" ::: "memory");
  }
  __builtin_amdgcn_s_barrier();
  __builtin_amdgcn_sched_barrier(0);

  for (int t = 0; t < KT; ++t) {
    const int b = t & 1, nb = b ^ 1;
    const bool hasT1 = (t + 1) < KT, hasT2 = (t + 2) < KT;
    short8 af[4], bf[4];

    // ---- P1: (mh=0, kk=0) ----
    #pragma unroll
    for (int mi = 0; mi < 4; ++mi)
      af[mi] = *(const short8*)&sA[b][0][(wm * 128 + mi * 16 + lr) * 32 + lsw8];
    #pragma unroll
    for (int ni = 0; ni < 4; ++ni)
      bf[ni] = *(const short8*)&sB[b][0][(wn * 64 + ni * 16 + lr) * 32 + lsw8];
    if (hasT1) { STA(nb, 1, t + 1) }
    __builtin_amdgcn_s_setprio(1);
    #pragma unroll
    for (int mi = 0; mi < 4; ++mi)
      #pragma unroll
      for (int ni = 0; ni < 4; ++ni)
        acc[mi][ni] = __builtin_amdgcn_mfma_f32_16x16x32_bf16(af[mi], bf[ni], acc[mi][ni], 0, 0, 0);
    __builtin_amdgcn_s_setprio(0);
    __builtin_amdgcn_s_barrier();

    // ---- P2: (mh=1, kk=0) ----
    #pragma unroll
    for (int mi = 0; mi < 4; ++mi)
      af[mi] = *(const short8*)&sA[b][0][(wm * 128 + (4 + mi) * 16 + lr) * 32 + lsw8];
    if (hasT2) { STB(b, 0, t + 2) }
    __builtin_amdgcn_s_setprio(1);
    #pragma unroll
    for (int mi = 0; mi < 4; ++mi)
      #pragma unroll
      for (int ni = 0; ni < 4; ++ni)
        acc[4 + mi][ni] = __builtin_amdgcn_mfma_f32_16x16x32_bf16(af[mi], bf[ni], acc[4 + mi][ni], 0, 0, 0);
    __builtin_amdgcn_s_setprio(0);
    __builtin_amdgcn_s_barrier();

    // ---- P3: (mh=0, kk=1) ----
    #pragma unroll
    for (int mi = 0; mi < 4; ++mi)
      af[mi] = *(const short8*)&sA[b][1][(wm * 128 + mi * 16 + lr) * 32 + lsw8];
    #pragma unroll
    for (int ni = 0; ni < 4; ++ni)
      bf[ni] = *(const short8*)&sB[b][1][(wn * 64 + ni * 16 + lr) * 32 + lsw8];
    if (hasT2) { STA(b, 0, t + 2) }
    __builtin_amdgcn_s_setprio(1);
    #pragma unroll
    for (int mi = 0; mi < 4; ++mi)
      #pragma unroll
      for (int ni = 0; ni < 4; ++ni)
        acc[mi][ni] = __builtin_amdgcn_mfma_f32_16x16x32_bf16(af[mi], bf[ni], acc[mi][ni], 0, 0, 0);
    __builtin_amdgcn_s_setprio(0);
    __builtin_amdgcn_s_barrier();

    // ---- P4: (mh=1, kk=1) ----
    #pragma unroll
    for (int mi = 0; mi < 4; ++mi)
      af[mi] = *(const short8*)&sA[b][1][(wm * 128 + (4 + mi) * 16 + lr) * 32 + lsw8];
    if (hasT2) { STB(b, 1, t + 2) }
    __builtin_amdgcn_s_setprio(1);
    #pragma unroll
    for (int mi = 0; mi < 4; ++mi)
      #pragma unroll
      for (int ni = 0; ni < 4; ++ni)
        acc[4 + mi][ni] = __builtin_amdgcn_mfma_f32_16x16x32_bf16(af[mi], bf[ni], acc[4 + mi][ni], 0, 0, 0);
    __builtin_amdgcn_s_setprio(0);
    if (t == KT - 2) {
      asm volatile("s_waitcnt vmcnt(0)" ::: "memory");
    } else if (t < KT - 2) {
      asm volatile("s_waitcnt vmcnt(6)" ::: "memory");
    }
    __builtin_amdgcn_s_barrier();
    __builtin_amdgcn_sched_barrier(0);
  }
#undef STA
#undef STB

  #pragma unroll
  for (int mi = 0; mi < 8; ++mi) {
    #pragma unroll
    for (int ni = 0; ni < 4; ++ni) {
      int row = bm * 256 + wm * 128 + mi * 16 + ls * 4;
      int col = bn * 256 + wn * 64 + ni * 16 + lr;
      #pragma unroll
      for (int r = 0; r < 4; ++r)
        C[(long long)(row + r) * ldc + col] = f2bf(acc[mi][ni][r]);
    }
  }
}

// ======== fused score+softmax+PV: one wg per (b,h), 1024 thr / 16 waves ========
// (round-10/11 proven) + dt=0 kvT staging hoisted before softmax (overlaps the
// softmax VALU work; kvT region is disjoint, first PV barrier publishes it).
// LDS carve (148 KiB): lds_a 9216 | lds_b 73728 (P aliases) | kvT 66560 | red 2048.
__global__ __launch_bounds__(1024, 1) void score_softmax_pv(
    const float* __restrict__ routers,      // f32 (8,64,256)
    const unsigned short* __restrict__ kv,  // (16384,2048): row b*512+n, col h*256+d
    float* __restrict__ attnw,              // (256,64,512) f32
    unsigned short* __restrict__ ao)        // (2048,2048): row b*64+r, col h*256+d
{
  __shared__ __align__(16) char smem[151552];
  unsigned short* lds_a = (unsigned short*)smem;                 // [64][72]
  unsigned short* lds_b = (unsigned short*)(smem + 9216);        // [512][72] kv tiles
  unsigned short* P_lds = (unsigned short*)(smem + 9216);        // [64][520] (aliases lds_b)
  unsigned short* kvT   = (unsigned short*)(smem + 82944);       // [64][520]
  float* redmax = (float*)(smem + 149504);                       // [64][4]
  float* redsum = (float*)(smem + 150528);                       // [64][4]

  const int bh = blockIdx.x;
  const int b = bh >> 3, h = bh & 7;
  const int tid = threadIdx.x;
  const int wave = tid >> 6, lane = tid & 63;
  const int wm = wave >> 2, wn = wave & 3;
  const int lr = lane & 15, ls = lane >> 4;
  const int lk = ls * 8;

  const unsigned short* kvb = kv + (long long)b * 512 * 2048 + h * 256;
  const float* Rh = routers + h * 16384;

#define STAGE_KVT(dt_) { _Pragma("unroll") \
    for (int i = 0; i < 4; ++i) { \
      int c = i * 1024 + tid; \
      int n = c & 511, dgrp = c >> 9; \
      uint4v v = *(const uint4v*)&kvb[(long long)n * 2048 + (dt_) * 64 + dgrp * 8]; \
      const unsigned short* pv = (const unsigned short*)&v; \
      _Pragma("unroll") \
      for (int j = 0; j < 8; ++j) kvT[(dgrp * 8 + j) * 520 + n] = pv[j]; \
    } }

  f32x4 acc[8];
  #pragma unroll
  for (int ni = 0; ni < 8; ++ni) acc[ni] = f32x4{0.f, 0.f, 0.f, 0.f};

  // ---- score ----
  for (int k0 = 0; k0 < 256; k0 += 64) {
    {
      int r = tid >> 4, kc = (tid & 15) * 4;
      float4 v = *(const float4*)(Rh + r * 256 + k0 + kc);
      ushort4v w; w.x = f2bf(v.x); w.y = f2bf(v.y); w.z = f2bf(v.z); w.w = f2bf(v.w);
      *(ushort4v*)&lds_a[r * 72 + kc] = w;
    }
    #pragma unroll
    for (int i = 0; i < 4; ++i) {
      int c = i * 1024 + tid;
      int r = c >> 3, kc = (c & 7) * 8;
      *(uint4v*)&lds_b[r * 72 + kc] = *(const uint4v*)(kvb + (long long)r * 2048 + k0 + kc);
    }
    __syncthreads();
    #pragma unroll
    for (int kk = 0; kk < 2; ++kk) {
      short8 af = *(const short8*)&lds_a[(wm * 16 + lr) * 72 + kk * 32 + lk];
      #pragma unroll
      for (int ni = 0; ni < 8; ++ni) {
        short8 bf = *(const short8*)&lds_b[(wn * 128 + ni * 16 + lr) * 72 + kk * 32 + lk];
        acc[ni] = __builtin_amdgcn_mfma_f32_16x16x32_bf16(af, bf, acc[ni], 0, 0, 0);
      }
    }
    __syncthreads();
  }

  // hoisted dt=0 kvT staging — overlaps softmax below (kvT disjoint; published
  // by the first PV __syncthreads)
  STAGE_KVT(0)

  // ---- softmax ----
  #pragma unroll
  for (int q = 0; q < 4; ++q) {
    int row = wm * 16 + ls * 4 + q;
    float m = -1e30f;
    #pragma unroll
    for (int ni = 0; ni < 8; ++ni) { acc[ni][q] *= 0.0625f; m = fmaxf(m, acc[ni][q]); }
    #pragma unroll
    for (int d = 1; d < 16; d <<= 1) m = fmaxf(m, __shfl_xor(m, d, 64));
    if (lr == 0) redmax[row * 4 + wn] = m;
  }
  __syncthreads();
  #pragma unroll
  for (int q = 0; q < 4; ++q) {
    int row = wm * 16 + ls * 4 + q;
    float M = fmaxf(fmaxf(redmax[row * 4 + 0], redmax[row * 4 + 1]),
                    fmaxf(redmax[row * 4 + 2], redmax[row * 4 + 3]));
    float s = 0.f;
    #pragma unroll
    for (int ni = 0; ni < 8; ++ni) { float p = __expf(acc[ni][q] - M); acc[ni][q] = p; s += p; }
    #pragma unroll
    for (int d = 1; d < 16; d <<= 1) s += __shfl_xor(s, d, 64);
    if (lr == 0) redsum[row * 4 + wn] = s;
  }
  __syncthreads();
  #pragma unroll
  for (int q = 0; q < 4; ++q) {
    int row = wm * 16 + ls * 4 + q;
    float inv = 1.0f / (redsum[row * 4 + 0] + redsum[row * 4 + 1] +
                        redsum[row * 4 + 2] + redsum[row * 4 + 3]);
    long long base = (long long)bh * 32768 + row * 512 + wn * 128;
    #pragma unroll
    for (int ni = 0; ni < 8; ++ni) {
      float wv = acc[ni][q] * inv;
      attnw[base + ni * 16 + lr] = wv;
      P_lds[row * 520 + wn * 128 + ni * 16 + lr] = f2bf(wv);   // aliases dead lds_b
    }
  }

  // ---- PV: 4 d-tiles of 64 (dt=0 staging already done) ----
  for (int dt = 0; dt < 4; ++dt) {
    if (dt != 0) { STAGE_KVT(dt) }
    __syncthreads();   // covers P_lds writes + kvT staging
    f32x4 accp = f32x4{0.f, 0.f, 0.f, 0.f};
    #pragma unroll
    for (int kk = 0; kk < 16; ++kk) {
      short8 af = *(const short8*)&P_lds[(wm * 16 + lr) * 520 + kk * 32 + lk];
      short8 bf = *(const short8*)&kvT[(wn * 16 + lr) * 520 + kk * 32 + lk];
      accp = __builtin_amdgcn_mfma_f32_16x16x32_bf16(af, bf, accp, 0, 0, 0);
    }
    #pragma unroll
    for (int q = 0; q < 4; ++q) {
      int r = wm * 16 + ls * 4 + q;
      ao[(long long)(b * 64 + r) * 2048 + h * 256 + dt * 64 + wn * 16 + lr] = f2bf(accp[q]);
    }
    __syncthreads();   // before next tile's kvT overwrite
  }
#undef STAGE_KVT
}

// ---------------- reg-staged GEMM (proj, split-K atomic) ----------------
template<int BM,int BN,int BK,int WM,int WN,bool DO_BIAS>
__global__ __launch_bounds__(256) void gemm_bt_splitk(
    const unsigned short* __restrict__ Ap, const unsigned short* __restrict__ Bp,
    float* __restrict__ Cv, const float* __restrict__ bias,
    int lda, int ldb, int ldc, int Kslice, int nWGn)
{
  constexpr int STRA = BK + 8;
  constexpr int STRB = BK + 8;
  constexpr int NWN = BN / WN;
  constexpr int MF = WM / 16, NF = WN / 16;
  __shared__ __align__(16) unsigned short lds_a[BM * STRA];
  __shared__ __align__(16) unsigned short lds_b[BN * STRB];

  const int tid = threadIdx.x;
  const int bn = blockIdx.x % nWGn;
  const int bm = blockIdx.x / nWGn;
  const int kp = blockIdx.y;

  const int wave = tid >> 6, lane = tid & 63;
  const int wm = wave / NWN, wn = wave % NWN;
  const int lr = lane & 15;
  const int lk = (lane >> 4) * 8;

  const long long abase = (long long)bm * BM * lda + (long long)kp * Kslice;
  const long long bbase = (long long)bn * BN * ldb + (long long)kp * Kslice;

  f32x4 acc[MF][NF];
  #pragma unroll
  for (int mi = 0; mi < MF; ++mi)
    #pragma unroll
    for (int ni = 0; ni < NF; ++ni)
      acc[mi][ni] = f32x4{0.f, 0.f, 0.f, 0.f};

  for (int k0 = 0; k0 < Kslice; k0 += BK) {
    {
      const unsigned short* Ab2 = Ap + abase + k0;
      #pragma unroll
      for (int i = 0; i < BM*BK/2048; ++i) {
        int c = i*256 + tid;
        int r = c / (BK/8);
        int kc = (c % (BK/8)) * 8;
        *(uint4v*)&lds_a[r*STRA + kc] = *(const uint4v*)(Ab2 + (long long)r*lda + kc);
      }
    }
    {
      const unsigned short* Bb2 = Bp + bbase + k0;
      #pragma unroll
      for (int i = 0; i < BN*BK/2048; ++i) {
        int c = i*256 + tid;
        int r = c / (BK/8);
        int kc = (c % (BK/8)) * 8;
        *(uint4v*)&lds_b[r*STRB + kc] = *(const uint4v*)(Bb2 + (long long)r*ldb + kc);
      }
    }
    __syncthreads();

    #pragma unroll
    for (int kk = 0; kk < BK/32; ++kk) {
      short8 af[MF]; short8 bfr[NF];
      #pragma unroll
      for (int mi = 0; mi < MF; ++mi)
        af[mi] = *(const short8*)&lds_a[(wm*WM + mi*16 + lr)*STRA + kk*32 + lk];
      #pragma unroll
      for (int ni = 0; ni < NF; ++ni)
        bfr[ni] = *(const short8*)&lds_b[(wn*WN + ni*16 + lr)*STRB + kk*32 + lk];
      #pragma unroll
      for (int mi = 0; mi < MF; ++mi)
        #pragma unroll
        for (int ni = 0; ni < NF; ++ni)
          acc[mi][ni] = __builtin_amdgcn_mfma_f32_16x16x32_bf16(af[mi], bfr[ni], acc[mi][ni], 0, 0, 0);
    }
    __syncthreads();
  }

  const int cr0 = (lane >> 4) * 4;
  #pragma unroll
  for (int mi = 0; mi < MF; ++mi) {
    #pragma unroll
    for (int ni = 0; ni < NF; ++ni) {
      int row = bm*BM + wm*WM + mi*16 + cr0;
      int col = bn*BN + wn*WN + ni*16 + lr;
      float badd = (DO_BIAS && kp == 0) ? bias[col] : 0.f;
      #pragma unroll
      for (int r = 0; r < 4; ++r) {
        float x = acc[mi][ni][r] + badd;
        unsafeAtomicAdd(&Cv[(long long)(row + r) * ldc + col], x);
      }
    }
  }
}

extern "C" void kernel_launch(void* const* d_in, const int* in_sizes, int n_in,
                              void* d_out, int out_size, void* d_ws, size_t ws_size,
                              hipStream_t stream) {
  const float* x       = (const float*)d_in[0];   // (32,512,1024)
  const float* routers = (const float*)d_in[1];   // (8,64,256)
  const float* wkv     = (const float*)d_in[2];   // (2048,1024)
  const float* projw   = (const float*)d_in[3];   // (1024,2048)
  const float* pbias   = (const float*)d_in[4];   // (1024,)

  char* ws = (char*)d_ws;
  unsigned short* wkv_b   = (unsigned short*)(ws);                //  4,194,304 B
  unsigned short* projw_b = (unsigned short*)(ws +  4194304);     //  4,194,304 B
  unsigned short* kv_b    = (unsigned short*)(ws +  8388608);     // 67,108,864 B (16384 x 2048)
  // region R: xb lives here ONLY during gemm1; ao_b reuses it afterwards.
  unsigned short* xb      = (unsigned short*)(ws + 75497472);     // 33,554,432 B (16384 x 1024)
  unsigned short* ao_b    = (unsigned short*)(ws + 92536832);     //  8,388,608 B (2048 x 2048)

  float* out0  = (float*)d_out;            // (32,64,1024)
  float* attnw = out0 + 2097152;           // (32,8,64,512) f32 softmax output

  // cast wkv | projw | x  +  zero out0 (5,767,168 float4 units)
  cast_all<<<22528, 256, 0, stream>>>(x, wkv, projw, xb, wkv_b, projw_b, out0);

  // kv = x @ wkv^T : M=16384 N=2048 K=1024 -> bf16 kv_b ; grid 64x8 = 512 wgs
  gemm1_8phase<<<512, 512, 0, stream>>>(xb, wkv_b, kv_b, 1024, 1024, 2048, 1024, 8);

  // fused S = routers@kv^T/16 + softmax -> attnw, then AO = P@kv -> ao_b; 1 wg per bh
  score_softmax_pv<<<256, 1024, 0, stream>>>(routers, kv_b, attnw, ao_b);

  // out += AO @ projw^T (+bias on kp==0) : M=2048 N=1024, K split 2x1024, atomic
  gemm_bt_splitk<64,128,64,64,32,true><<<dim3(256,2), 256, 0, stream>>>(
      ao_b, projw_b, out0, pbias, 2048, 2048, 1024, 1024, 8);
}